// Round 12
// baseline (270.745 us; speedup 1.0000x reference)
//
#include <hip/hip_runtime.h>
#include <math.h>

// Problem constants
#define B_ 4
#define S_ 2048
#define E_ 512
#define H_ 8
#define D_ 64

typedef short bf16x8 __attribute__((ext_vector_type(8)));
typedef float f32x4 __attribute__((ext_vector_type(4)));

typedef __attribute__((address_space(3))) void lds_void;
typedef const __attribute__((address_space(1))) void gbl_void;

__device__ inline void async16(short* lds_base, const short* gsrc) {
  // wave-uniform LDS base + lane*16; per-lane global src (guide §5 caveat)
  __builtin_amdgcn_global_load_lds((gbl_void*)gsrc, (lds_void*)lds_base, 16, 0, 0);
}

__device__ inline short f2bf(float f) {  // fp32 -> bf16 bits, RNE
  union { float f; unsigned u; } v; v.f = f;
  unsigned r = v.u + 0x7FFF + ((v.u >> 16) & 1);
  return (short)(r >> 16);
}
__device__ inline short f2bf_fast(float f) {  // round-half-up (P matrix only)
  union { float f; unsigned u; } v; v.f = f;
  return (short)((v.u + 0x8000u) >> 16);
}
__device__ inline float bf2f(short s) {
  union { unsigned u; float f; } v; v.u = ((unsigned)(unsigned short)s) << 16;
  return v.f;
}

// ---------------------------------------------------------------------------
// fused fp32->bf16 convert for X, W_in, W_out in ONE launch (block ranges)
// ---------------------------------------------------------------------------
__global__ __launch_bounds__(256) void cvt_all(
    const float* __restrict__ x, const float* __restrict__ win,
    const float* __restrict__ wout, short* __restrict__ xb,
    short* __restrict__ winb, short* __restrict__ woutb) {
  int bid = blockIdx.x;
  const float* src; short* dst; int i;
  if (bid < 4096)      { src = x;    dst = xb;    i = bid * 256 + threadIdx.x; }
  else if (bid < 4864) { src = win;  dst = winb;  i = (bid - 4096) * 256 + threadIdx.x; }
  else                 { src = wout; dst = woutb; i = (bid - 4864) * 256 + threadIdx.x; }
  float4 f = ((const float4*)src)[i];
  short4 o;
  o.x = f2bf(f.x); o.y = f2bf(f.y); o.z = f2bf(f.z); o.w = f2bf(f.w);
  ((short4*)dst)[i] = o;
}

// ---------------------------------------------------------------------------
// MFMA GEMM 128x128 tile, BK=32, 4 waves (2x2), m97-style async staging:
// global_load_lds width=16, unpadded LDS [128][32]. gemm_qkv epilogue fuses
// RoPE (fast __sincosf); q,k stored [bh][s][d]; V TRANSPOSED [bh][d][s].
// ---------------------------------------------------------------------------
__global__ __launch_bounds__(256) void gemm_qkv_mfma(
    const short* __restrict__ Xb,    // [8192][512] bf16
    const short* __restrict__ Wb,    // [1536][512] bf16
    short* __restrict__ qb, short* __restrict__ kb, short* __restrict__ vbT) {
  __shared__ __align__(16) short As[128][32];
  __shared__ __align__(16) short Bs[128][32];
  const int tid = threadIdx.x;
  const int w = tid >> 6, lane = tid & 63;
  const int l15 = lane & 15, quad = lane >> 4;
  const int wm = w & 1, wn = w >> 1;
  const int m0 = blockIdx.x * 128;
  const int n0 = blockIdx.y * 128;
  // staging coords: wave w covers rows [w*32, w*32+32), 16 rows/instruction
  const int srow = w * 32 + (lane >> 2);
  const int scol = (lane & 3) * 8;
  const short* gA0 = &Xb[(size_t)(m0 + srow) * E_ + scol];
  const short* gA1 = &Xb[(size_t)(m0 + srow + 16) * E_ + scol];
  const short* gB0 = &Wb[(size_t)(n0 + srow) * E_ + scol];
  const short* gB1 = &Wb[(size_t)(n0 + srow + 16) * E_ + scol];
  short* lA0 = &As[w * 32][0];
  short* lA1 = &As[w * 32 + 16][0];
  short* lB0 = &Bs[w * 32][0];
  short* lB1 = &Bs[w * 32 + 16][0];
  f32x4 acc[4][4];
  for (int mt = 0; mt < 4; ++mt)
    for (int nt = 0; nt < 4; ++nt) acc[mt][nt] = (f32x4){0.f, 0.f, 0.f, 0.f};

  for (int k0 = 0; k0 < E_; k0 += 32) {
    __syncthreads();                       // prior tile consumed
    async16(lA0, gA0 + k0);
    async16(lA1, gA1 + k0);
    async16(lB0, gB0 + k0);
    async16(lB1, gB1 + k0);
    __syncthreads();                       // vmcnt drained by compiler
    bf16x8 a[4], bfr[4];
    for (int mt = 0; mt < 4; ++mt)
      a[mt] = *(const bf16x8*)&As[wm * 64 + mt * 16 + l15][quad * 8];
    for (int nt = 0; nt < 4; ++nt)
      bfr[nt] = *(const bf16x8*)&Bs[wn * 64 + nt * 16 + l15][quad * 8];
    for (int mt = 0; mt < 4; ++mt)
      for (int nt = 0; nt < 4; ++nt)
        acc[mt][nt] = __builtin_amdgcn_mfma_f32_16x16x32_bf16(a[mt], bfr[nt], acc[mt][nt], 0, 0, 0);
  }
  const int t3 = n0 >> 9;                  // uniform per block: 0=q 1=k 2=v
  for (int nt = 0; nt < 4; ++nt) {
    const int n = n0 + wn * 64 + nt * 16 + l15;
    const int h = (n >> 6) & 7;
    const int d = n & 63;
    const bool dorope = (t3 < 2) && (d < 32);
    const float sgn = (d & 1) ? 1.f : -1.f;
    const float fr = dorope ? powf(10000.f, -(float)(2 * (d >> 1)) * (1.f / 32.f)) : 0.f;
    for (int mt = 0; mt < 4; ++mt) {
      for (int i = 0; i < 4; ++i) {
        const int m = m0 + wm * 64 + mt * 16 + quad * 4 + i;
        const int b = m >> 11, s = m & (S_ - 1);
        float val = acc[mt][nt][i];
        float pv = __shfl_xor(val, 1, 64);
        float outv = val;
        if (dorope) {
          float sn, cs;
          __sincosf((float)s * fr, &sn, &cs);
          outv = val * cs + pv * sgn * sn;
        }
        if (t3 == 2)
          vbT[((size_t)(b * 8 + h) * D_ + d) * S_ + s] = f2bf(outv);
        else {
          short* dst = (t3 == 0) ? qb : kb;
          dst[(((size_t)(b * 8 + h)) * S_ + s) * D_ + d] = f2bf(outv);
        }
      }
    }
  }
}

// ---------------------------------------------------------------------------
// gemm_out: out = ob @ Woutb^T, fp32 output; same async staging
// ---------------------------------------------------------------------------
__global__ __launch_bounds__(256) void gemm_out_mfma(
    const short* __restrict__ Ab, const short* __restrict__ Wb,
    float* __restrict__ out) {
  __shared__ __align__(16) short As[128][32];
  __shared__ __align__(16) short Bs[128][32];
  const int tid = threadIdx.x;
  const int w = tid >> 6, lane = tid & 63;
  const int l15 = lane & 15, quad = lane >> 4;
  const int wm = w & 1, wn = w >> 1;
  const int m0 = blockIdx.x * 128;
  const int n0 = blockIdx.y * 128;
  const int srow = w * 32 + (lane >> 2);
  const int scol = (lane & 3) * 8;
  const short* gA0 = &Ab[(size_t)(m0 + srow) * E_ + scol];
  const short* gA1 = &Ab[(size_t)(m0 + srow + 16) * E_ + scol];
  const short* gB0 = &Wb[(size_t)(n0 + srow) * E_ + scol];
  const short* gB1 = &Wb[(size_t)(n0 + srow + 16) * E_ + scol];
  short* lA0 = &As[w * 32][0];
  short* lA1 = &As[w * 32 + 16][0];
  short* lB0 = &Bs[w * 32][0];
  short* lB1 = &Bs[w * 32 + 16][0];
  f32x4 acc[4][4];
  for (int mt = 0; mt < 4; ++mt)
    for (int nt = 0; nt < 4; ++nt) acc[mt][nt] = (f32x4){0.f, 0.f, 0.f, 0.f};

  for (int k0 = 0; k0 < E_; k0 += 32) {
    __syncthreads();
    async16(lA0, gA0 + k0);
    async16(lA1, gA1 + k0);
    async16(lB0, gB0 + k0);
    async16(lB1, gB1 + k0);
    __syncthreads();
    bf16x8 a[4], bfr[4];
    for (int mt = 0; mt < 4; ++mt)
      a[mt] = *(const bf16x8*)&As[wm * 64 + mt * 16 + l15][quad * 8];
    for (int nt = 0; nt < 4; ++nt)
      bfr[nt] = *(const bf16x8*)&Bs[wn * 64 + nt * 16 + l15][quad * 8];
    for (int mt = 0; mt < 4; ++mt)
      for (int nt = 0; nt < 4; ++nt)
        acc[mt][nt] = __builtin_amdgcn_mfma_f32_16x16x32_bf16(a[mt], bfr[nt], acc[mt][nt], 0, 0, 0);
  }
  for (int mt = 0; mt < 4; ++mt)
    for (int nt = 0; nt < 4; ++nt) {
      const int n = n0 + wn * 64 + nt * 16 + l15;
      for (int i = 0; i < 4; ++i) {
        const int m = m0 + wm * 64 + mt * 16 + quad * 4 + i;
        out[(size_t)m * E_ + n] = acc[mt][nt][i];
      }
    }
}

// ---------------------------------------------------------------------------
// Flash attention, MFMA, static-max softmax, SPLIT-K (unchanged from r11).
// ---------------------------------------------------------------------------
__global__ __launch_bounds__(256) void flash_mfma(
    const short* __restrict__ qb, const short* __restrict__ kb,
    const short* __restrict__ vbT, const int* __restrict__ maskp,
    short* __restrict__ pb0, short* __restrict__ pb1,
    float* __restrict__ lb0, float* __restrict__ lb1,
    short* __restrict__ ob) {
  __shared__ __align__(16) short Ks[64][72];
  __shared__ __align__(16) short VT[64][72];
  __shared__ __align__(16) short Pl[4][16][72];
  __shared__ float kbias[64];
  const int tid = threadIdx.x;
  const int w = tid >> 6, lane = tid & 63;
  const int l15 = lane & 15, quad = lane >> 4;
  const int bid = blockIdx.x;
  const int u = bid & 7, v = bid >> 3;       // u -> XCD under id&7 model
  const int bh = (u << 2) | (v & 3);         // 4 bh per XCD
  const int w2 = v >> 2;                     // 0..31
  const int pair = w2 & 15;                  // q-tile pair id
  const int kh = w2 >> 4;                    // split half: 0 or 1
  const int b = bh >> 3, hd = bh & 7;
  const short* qbase = qb + (size_t)bh * S_ * D_;
  const short* kbase = kb + (size_t)bh * S_ * D_;
  const short* vtb   = vbT + (size_t)bh * D_ * S_;
  short* PB = kh ? pb1 : pb0;
  float* LB = kh ? lb1 : lb0;
  const float c2 = 0.1803368801f;            // 0.125 * log2(e)
  bf16x8 ones;
  for (int j = 0; j < 8; ++j) ones[j] = (short)0x3F80;  // bf16 1.0

  for (int seg = 0; seg < 2; ++seg) {
    const int qt = (seg == 0) ? pair : 31 - pair;
    const int r0 = qt * 64;
    const int mid = (qt + 2) >> 1;           // ceil((qt+1)/2)
    const int lo = kh ? mid : 0;
    const int hi = kh ? (qt + 1) : mid;
    bf16x8 aq[2];
    {
      const short* qrow = qbase + (size_t)(r0 + 16 * w + l15) * D_;
      aq[0] = *(const bf16x8*)&qrow[quad * 8];
      aq[1] = *(const bf16x8*)&qrow[32 + quad * 8];
    }
    f32x4 o[4], lsum;
    for (int no = 0; no < 4; ++no) o[no] = (f32x4){0.f, 0.f, 0.f, 0.f};
    lsum = (f32x4){0.f, 0.f, 0.f, 0.f};

    for (int kt = lo; kt < hi; ++kt) {
      const int t0 = kt * 64;
      __syncthreads();                       // prior tile fully consumed
      for (int l = 0; l < 2; ++l) {
        int idx = tid + 256 * l;
        int row = idx >> 3, ch = (idx & 7) * 8;
        *(bf16x8*)&Ks[row][ch] = *(const bf16x8*)(kbase + (size_t)(t0 + row) * D_ + ch);
        *(bf16x8*)&VT[row][ch] = *(const bf16x8*)(vtb + (size_t)row * S_ + t0 + ch);
      }
      if (tid < 64)
        kbias[tid] = maskp[b * S_ + t0 + tid] ? -23.08312f : -1.0e38f;
      __syncthreads();
      f32x4 sfr[4];
      for (int nb = 0; nb < 4; ++nb) sfr[nb] = (f32x4){0.f, 0.f, 0.f, 0.f};
      for (int nb = 0; nb < 4; ++nb)
        for (int ks = 0; ks < 2; ++ks) {
          bf16x8 bk = *(const bf16x8*)&Ks[l15 + 16 * nb][32 * ks + quad * 8];
          sfr[nb] = __builtin_amdgcn_mfma_f32_16x16x32_bf16(aq[ks], bk, sfr[nb], 0, 0, 0);
        }
      if (kt < qt) {                         // interior tiles: no causal test
        for (int nb = 0; nb < 4; ++nb) {
          const float bb = kbias[l15 + 16 * nb];
          for (int i = 0; i < 4; ++i)
            Pl[w][quad * 4 + i][l15 + 16 * nb] = f2bf_fast(exp2f(sfr[nb][i] * c2 + bb));
        }
      } else {                               // boundary tile: add causal mask
        for (int nb = 0; nb < 4; ++nb) {
          const int tg = l15 + 16 * nb;
          const float bb = kbias[l15 + 16 * nb];
          for (int i = 0; i < 4; ++i) {
            const float bbi = (tg > 16 * w + quad * 4 + i) ? -1.0e38f : bb;
            Pl[w][quad * 4 + i][l15 + 16 * nb] = f2bf_fast(exp2f(sfr[nb][i] * c2 + bbi));
          }
        }
      }
      asm volatile("s_waitcnt lgkmcnt(0)" ::: "memory");  // own-wave Pl writes
      bf16x8 ap0 = *(const bf16x8*)&Pl[w][l15][quad * 8];
      bf16x8 ap1 = *(const bf16x8*)&Pl[w][l15][32 + quad * 8];
      for (int no = 0; no < 4; ++no) {
        bf16x8 bv0 = *(const bf16x8*)&VT[16 * no + l15][quad * 8];
        bf16x8 bv1 = *(const bf16x8*)&VT[16 * no + l15][32 + quad * 8];
        o[no] = __builtin_amdgcn_mfma_f32_16x16x32_bf16(ap0, bv0, o[no], 0, 0, 0);
        o[no] = __builtin_amdgcn_mfma_f32_16x16x32_bf16(ap1, bv1, o[no], 0, 0, 0);
      }
      lsum = __builtin_amdgcn_mfma_f32_16x16x32_bf16(ap0, ones, lsum, 0, 0, 0);
      lsum = __builtin_amdgcn_mfma_f32_16x16x32_bf16(ap1, ones, lsum, 0, 0, 0);
    }
    // epilogue: write partials; kh=0 also writes V rows for masked queries
    for (int i = 0; i < 4; ++i) {
      const int s = r0 + 16 * w + quad * 4 + i;
      const int qm = maskp[b * S_ + s];
      const size_t row = (size_t)(b * S_ + s) * E_ + hd * D_;
      if (kh == 0 && !qm) {
        for (int no = 0; no < 4; ++no) {
          const int d = l15 + 16 * no;
          ob[row + d] = vtb[(size_t)d * S_ + s];
        }
      }
      for (int no = 0; no < 4; ++no)
        PB[row + l15 + 16 * no] = f2bf(o[no][i]);
      if (l15 == 0)
        LB[bh * S_ + s] = lsum[i];
    }
  }
}

// ---------------------------------------------------------------------------
// merge: ob[m][e] = (P0 + P1) / (l0 + l1) for unmasked rows
// ---------------------------------------------------------------------------
__global__ __launch_bounds__(256) void merge_kernel(
    const short* __restrict__ pb0, const short* __restrict__ pb1,
    const float* __restrict__ lb0, const float* __restrict__ lb1,
    const int* __restrict__ maskp, short* __restrict__ ob) {
  int idx = blockIdx.x * 256 + threadIdx.x;  // 8192*64 threads
  int m = idx >> 6, e = (idx & 63) * 8;
  if (!maskp[m]) return;                     // masked row: flash wrote V
  int b = m >> 11, s = m & (S_ - 1);
  int bh = b * 8 + (e >> 6);
  float l = lb0[bh * S_ + s] + lb1[bh * S_ + s];
  float inv = 1.f / l;
  bf16x8 p0 = *(const bf16x8*)&pb0[(size_t)m * E_ + e];
  bf16x8 p1 = *(const bf16x8*)&pb1[(size_t)m * E_ + e];
  bf16x8 r;
  for (int j = 0; j < 8; ++j)
    r[j] = f2bf((bf2f(p0[j]) + bf2f(p1[j])) * inv);
  *(bf16x8*)&ob[(size_t)m * E_ + e] = r;
}

extern "C" void kernel_launch(void* const* d_in, const int* in_sizes, int n_in,
                              void* d_out, int out_size, void* d_ws, size_t ws_size,
                              hipStream_t stream) {
  const float* x    = (const float*)d_in[0];
  const int*   mask = (const int*)d_in[1];
  const float* Win  = (const float*)d_in[2];
  const float* Wout = (const float*)d_in[3];
  float* out = (float*)d_out;

  short* Xb    = (short*)d_ws;               // 8192*512
  short* Winb  = Xb + 8192 * 512;            // 1536*512
  short* Woutb = Winb + 1536 * 512;          // 512*512
  short* qb    = Woutb + 512 * 512;          // 32*2048*64 each
  short* kb    = qb + 32 * 2048 * 64;
  short* vbT   = kb + 32 * 2048 * 64;        // [bh][d][s] transposed
  short* ob    = vbT + 32 * 2048 * 64;       // 8192*512
  short* pb0   = ob + 8192 * 512;            // partial O, half 0 (bf16)
  short* pb1   = pb0 + 8192 * 512;           // partial O, half 1
  float* lb0   = (float*)(pb1 + 8192 * 512); // lsum partials [32][2048]
  float* lb1   = lb0 + 32 * 2048;            // total ws ~61.3 MB

  cvt_all<<<5120, 256, 0, stream>>>(x, Win, Wout, Xb, Winb, Woutb);
  gemm_qkv_mfma<<<dim3(64, 12), 256, 0, stream>>>(Xb, Winb, qb, kb, vbT);
  flash_mfma<<<1024, 256, 0, stream>>>(qb, kb, vbT, mask, pb0, pb1, lb0, lb1, ob);
  merge_kernel<<<2048, 256, 0, stream>>>(pb0, pb1, lb0, lb1, mask, ob);
  gemm_out_mfma<<<dim3(64, 4), 256, 0, stream>>>(ob, Woutb, out);
}

// Round 13
// 265.669 us; speedup vs baseline: 1.0191x; 1.0191x over previous
//
#include <hip/hip_runtime.h>
#include <math.h>

// Problem constants
#define B_ 4
#define S_ 2048
#define E_ 512
#define H_ 8
#define D_ 64

typedef short bf16x8 __attribute__((ext_vector_type(8)));
typedef float f32x4 __attribute__((ext_vector_type(4)));

__device__ inline short f2bf(float f) {  // fp32 -> bf16 bits, RNE
  union { float f; unsigned u; } v; v.f = f;
  unsigned r = v.u + 0x7FFF + ((v.u >> 16) & 1);
  return (short)(r >> 16);
}
__device__ inline short f2bf_fast(float f) {  // round-half-up (P matrix only)
  union { float f; unsigned u; } v; v.f = f;
  return (short)((v.u + 0x8000u) >> 16);
}
__device__ inline float bf2f(short s) {
  union { unsigned u; float f; } v; v.u = ((unsigned)(unsigned short)s) << 16;
  return v.f;
}

// ---------------------------------------------------------------------------
// fused fp32->bf16 convert for X, W_in, W_out in ONE launch (block ranges)
// ---------------------------------------------------------------------------
__global__ __launch_bounds__(256) void cvt_all(
    const float* __restrict__ x, const float* __restrict__ win,
    const float* __restrict__ wout, short* __restrict__ xb,
    short* __restrict__ winb, short* __restrict__ woutb) {
  int bid = blockIdx.x;
  const float* src; short* dst; int i;
  if (bid < 4096)      { src = x;    dst = xb;    i = bid * 256 + threadIdx.x; }
  else if (bid < 4864) { src = win;  dst = winb;  i = (bid - 4096) * 256 + threadIdx.x; }
  else                 { src = wout; dst = woutb; i = (bid - 4864) * 256 + threadIdx.x; }
  float4 f = ((const float4*)src)[i];
  short4 o;
  o.x = f2bf(f.x); o.y = f2bf(f.y); o.z = f2bf(f.z); o.w = f2bf(f.w);
  ((short4*)dst)[i] = o;
}

// ---------------------------------------------------------------------------
// MFMA GEMM 128x128 tile, BK=32, 4 waves (2x2). REVERTED to r11 VGPR-round-
// trip staging (r12's global_load_lds regressed 53->140 us: WRITE_SIZE
// 25 MB -> 750 MB = scratch-bounce lowering of the builtin; do not re-try
// without disasm proof). NEW: r10-validated single-barrier register
// double-buffer (prefetch next K-slab to regs -> compute buf[cur] -> write
// buf[cur^1] -> one barrier). Epilogue fuses RoPE (__sincosf); q,k stored
// [bh][s][d]; V TRANSPOSED [bh][d][s].
// ---------------------------------------------------------------------------
__global__ __launch_bounds__(256) void gemm_qkv_mfma(
    const short* __restrict__ Xb,    // [8192][512] bf16
    const short* __restrict__ Wb,    // [1536][512] bf16
    short* __restrict__ qb, short* __restrict__ kb, short* __restrict__ vbT) {
  __shared__ __align__(16) short As[2][128][40];
  __shared__ __align__(16) short Bs[2][128][40];
  const int tid = threadIdx.x;
  const int w = tid >> 6, lane = tid & 63;
  const int l15 = lane & 15, quad = lane >> 4;
  const int wm = w & 1, wn = w >> 1;
  const int m0 = blockIdx.x * 128;
  const int n0 = blockIdx.y * 128;
  // staging coords: thread covers chunks tid and tid+256 (of 512 8-short chunks)
  const int r0s = tid >> 2,        k80 = (tid & 3) * 8;
  const int r1s = (tid + 256) >> 2, k81 = ((tid + 256) & 3) * 8;
  const short* gA0 = &Xb[(size_t)(m0 + r0s) * E_ + k80];
  const short* gA1 = &Xb[(size_t)(m0 + r1s) * E_ + k81];
  const short* gB0 = &Wb[(size_t)(n0 + r0s) * E_ + k80];
  const short* gB1 = &Wb[(size_t)(n0 + r1s) * E_ + k81];
  f32x4 acc[4][4];
  for (int mt = 0; mt < 4; ++mt)
    for (int nt = 0; nt < 4; ++nt) acc[mt][nt] = (f32x4){0.f, 0.f, 0.f, 0.f};

  // prologue: stage K-slab 0 into buf 0
  bf16x8 ra0 = *(const bf16x8*)gA0;
  bf16x8 ra1 = *(const bf16x8*)gA1;
  bf16x8 rb0 = *(const bf16x8*)gB0;
  bf16x8 rb1 = *(const bf16x8*)gB1;
  *(bf16x8*)&As[0][r0s][k80] = ra0;
  *(bf16x8*)&As[0][r1s][k81] = ra1;
  *(bf16x8*)&Bs[0][r0s][k80] = rb0;
  *(bf16x8*)&Bs[0][r1s][k81] = rb1;
  __syncthreads();

  for (int kt = 0; kt < 16; ++kt) {
    const int cur = kt & 1;
    if (kt < 15) {                         // issue next slab's loads early
      const int k0 = (kt + 1) * 32;
      ra0 = *(const bf16x8*)(gA0 + k0);
      ra1 = *(const bf16x8*)(gA1 + k0);
      rb0 = *(const bf16x8*)(gB0 + k0);
      rb1 = *(const bf16x8*)(gB1 + k0);
    }
    bf16x8 a[4], bfr[4];
    for (int mt = 0; mt < 4; ++mt)
      a[mt] = *(const bf16x8*)&As[cur][wm * 64 + mt * 16 + l15][quad * 8];
    for (int nt = 0; nt < 4; ++nt)
      bfr[nt] = *(const bf16x8*)&Bs[cur][wn * 64 + nt * 16 + l15][quad * 8];
    for (int mt = 0; mt < 4; ++mt)
      for (int nt = 0; nt < 4; ++nt)
        acc[mt][nt] = __builtin_amdgcn_mfma_f32_16x16x32_bf16(a[mt], bfr[nt], acc[mt][nt], 0, 0, 0);
    if (kt < 15) {                         // write to other buffer (its readers
      const int nxt = cur ^ 1;             // finished at the previous barrier)
      *(bf16x8*)&As[nxt][r0s][k80] = ra0;
      *(bf16x8*)&As[nxt][r1s][k81] = ra1;
      *(bf16x8*)&Bs[nxt][r0s][k80] = rb0;
      *(bf16x8*)&Bs[nxt][r1s][k81] = rb1;
    }
    __syncthreads();
  }
  const int t3 = n0 >> 9;                  // uniform per block: 0=q 1=k 2=v
  for (int nt = 0; nt < 4; ++nt) {
    const int n = n0 + wn * 64 + nt * 16 + l15;
    const int h = (n >> 6) & 7;
    const int d = n & 63;
    const bool dorope = (t3 < 2) && (d < 32);
    const float sgn = (d & 1) ? 1.f : -1.f;
    const float fr = dorope ? powf(10000.f, -(float)(2 * (d >> 1)) * (1.f / 32.f)) : 0.f;
    for (int mt = 0; mt < 4; ++mt) {
      for (int i = 0; i < 4; ++i) {
        const int m = m0 + wm * 64 + mt * 16 + quad * 4 + i;
        const int b = m >> 11, s = m & (S_ - 1);
        float val = acc[mt][nt][i];
        float pv = __shfl_xor(val, 1, 64);
        float outv = val;
        if (dorope) {
          float sn, cs;
          __sincosf((float)s * fr, &sn, &cs);
          outv = val * cs + pv * sgn * sn;
        }
        if (t3 == 2)
          vbT[((size_t)(b * 8 + h) * D_ + d) * S_ + s] = f2bf(outv);
        else {
          short* dst = (t3 == 0) ? qb : kb;
          dst[(((size_t)(b * 8 + h)) * S_ + s) * D_ + d] = f2bf(outv);
        }
      }
    }
  }
}

// ---------------------------------------------------------------------------
// gemm_out: out = ob @ Woutb^T, fp32 output; same reverted dbuf staging
// ---------------------------------------------------------------------------
__global__ __launch_bounds__(256) void gemm_out_mfma(
    const short* __restrict__ Ab, const short* __restrict__ Wb,
    float* __restrict__ out) {
  __shared__ __align__(16) short As[2][128][40];
  __shared__ __align__(16) short Bs[2][128][40];
  const int tid = threadIdx.x;
  const int w = tid >> 6, lane = tid & 63;
  const int l15 = lane & 15, quad = lane >> 4;
  const int wm = w & 1, wn = w >> 1;
  const int m0 = blockIdx.x * 128;
  const int n0 = blockIdx.y * 128;
  const int r0s = tid >> 2,        k80 = (tid & 3) * 8;
  const int r1s = (tid + 256) >> 2, k81 = ((tid + 256) & 3) * 8;
  const short* gA0 = &Ab[(size_t)(m0 + r0s) * E_ + k80];
  const short* gA1 = &Ab[(size_t)(m0 + r1s) * E_ + k81];
  const short* gB0 = &Wb[(size_t)(n0 + r0s) * E_ + k80];
  const short* gB1 = &Wb[(size_t)(n0 + r1s) * E_ + k81];
  f32x4 acc[4][4];
  for (int mt = 0; mt < 4; ++mt)
    for (int nt = 0; nt < 4; ++nt) acc[mt][nt] = (f32x4){0.f, 0.f, 0.f, 0.f};

  bf16x8 ra0 = *(const bf16x8*)gA0;
  bf16x8 ra1 = *(const bf16x8*)gA1;
  bf16x8 rb0 = *(const bf16x8*)gB0;
  bf16x8 rb1 = *(const bf16x8*)gB1;
  *(bf16x8*)&As[0][r0s][k80] = ra0;
  *(bf16x8*)&As[0][r1s][k81] = ra1;
  *(bf16x8*)&Bs[0][r0s][k80] = rb0;
  *(bf16x8*)&Bs[0][r1s][k81] = rb1;
  __syncthreads();

  for (int kt = 0; kt < 16; ++kt) {
    const int cur = kt & 1;
    if (kt < 15) {
      const int k0 = (kt + 1) * 32;
      ra0 = *(const bf16x8*)(gA0 + k0);
      ra1 = *(const bf16x8*)(gA1 + k0);
      rb0 = *(const bf16x8*)(gB0 + k0);
      rb1 = *(const bf16x8*)(gB1 + k0);
    }
    bf16x8 a[4], bfr[4];
    for (int mt = 0; mt < 4; ++mt)
      a[mt] = *(const bf16x8*)&As[cur][wm * 64 + mt * 16 + l15][quad * 8];
    for (int nt = 0; nt < 4; ++nt)
      bfr[nt] = *(const bf16x8*)&Bs[cur][wn * 64 + nt * 16 + l15][quad * 8];
    for (int mt = 0; mt < 4; ++mt)
      for (int nt = 0; nt < 4; ++nt)
        acc[mt][nt] = __builtin_amdgcn_mfma_f32_16x16x32_bf16(a[mt], bfr[nt], acc[mt][nt], 0, 0, 0);
    if (kt < 15) {
      const int nxt = cur ^ 1;
      *(bf16x8*)&As[nxt][r0s][k80] = ra0;
      *(bf16x8*)&As[nxt][r1s][k81] = ra1;
      *(bf16x8*)&Bs[nxt][r0s][k80] = rb0;
      *(bf16x8*)&Bs[nxt][r1s][k81] = rb1;
    }
    __syncthreads();
  }
  for (int mt = 0; mt < 4; ++mt)
    for (int nt = 0; nt < 4; ++nt) {
      const int n = n0 + wn * 64 + nt * 16 + l15;
      for (int i = 0; i < 4; ++i) {
        const int m = m0 + wm * 64 + mt * 16 + quad * 4 + i;
        out[(size_t)m * E_ + n] = acc[mt][nt][i];
      }
    }
}

// ---------------------------------------------------------------------------
// Flash attention, MFMA, static-max softmax, SPLIT-K (unchanged from r11).
// ---------------------------------------------------------------------------
__global__ __launch_bounds__(256) void flash_mfma(
    const short* __restrict__ qb, const short* __restrict__ kb,
    const short* __restrict__ vbT, const int* __restrict__ maskp,
    short* __restrict__ pb0, short* __restrict__ pb1,
    float* __restrict__ lb0, float* __restrict__ lb1,
    short* __restrict__ ob) {
  __shared__ __align__(16) short Ks[64][72];
  __shared__ __align__(16) short VT[64][72];
  __shared__ __align__(16) short Pl[4][16][72];
  __shared__ float kbias[64];
  const int tid = threadIdx.x;
  const int w = tid >> 6, lane = tid & 63;
  const int l15 = lane & 15, quad = lane >> 4;
  const int bid = blockIdx.x;
  const int u = bid & 7, v = bid >> 3;       // u -> XCD under id&7 model
  const int bh = (u << 2) | (v & 3);         // 4 bh per XCD
  const int w2 = v >> 2;                     // 0..31
  const int pair = w2 & 15;                  // q-tile pair id
  const int kh = w2 >> 4;                    // split half: 0 or 1
  const int b = bh >> 3, hd = bh & 7;
  const short* qbase = qb + (size_t)bh * S_ * D_;
  const short* kbase = kb + (size_t)bh * S_ * D_;
  const short* vtb   = vbT + (size_t)bh * D_ * S_;
  short* PB = kh ? pb1 : pb0;
  float* LB = kh ? lb1 : lb0;
  const float c2 = 0.1803368801f;            // 0.125 * log2(e)
  bf16x8 ones;
  for (int j = 0; j < 8; ++j) ones[j] = (short)0x3F80;  // bf16 1.0

  for (int seg = 0; seg < 2; ++seg) {
    const int qt = (seg == 0) ? pair : 31 - pair;
    const int r0 = qt * 64;
    const int mid = (qt + 2) >> 1;           // ceil((qt+1)/2)
    const int lo = kh ? mid : 0;
    const int hi = kh ? (qt + 1) : mid;
    bf16x8 aq[2];
    {
      const short* qrow = qbase + (size_t)(r0 + 16 * w + l15) * D_;
      aq[0] = *(const bf16x8*)&qrow[quad * 8];
      aq[1] = *(const bf16x8*)&qrow[32 + quad * 8];
    }
    f32x4 o[4], lsum;
    for (int no = 0; no < 4; ++no) o[no] = (f32x4){0.f, 0.f, 0.f, 0.f};
    lsum = (f32x4){0.f, 0.f, 0.f, 0.f};

    for (int kt = lo; kt < hi; ++kt) {
      const int t0 = kt * 64;
      __syncthreads();                       // prior tile fully consumed
      for (int l = 0; l < 2; ++l) {
        int idx = tid + 256 * l;
        int row = idx >> 3, ch = (idx & 7) * 8;
        *(bf16x8*)&Ks[row][ch] = *(const bf16x8*)(kbase + (size_t)(t0 + row) * D_ + ch);
        *(bf16x8*)&VT[row][ch] = *(const bf16x8*)(vtb + (size_t)row * S_ + t0 + ch);
      }
      if (tid < 64)
        kbias[tid] = maskp[b * S_ + t0 + tid] ? -23.08312f : -1.0e38f;
      __syncthreads();
      f32x4 sfr[4];
      for (int nb = 0; nb < 4; ++nb) sfr[nb] = (f32x4){0.f, 0.f, 0.f, 0.f};
      for (int nb = 0; nb < 4; ++nb)
        for (int ks = 0; ks < 2; ++ks) {
          bf16x8 bk = *(const bf16x8*)&Ks[l15 + 16 * nb][32 * ks + quad * 8];
          sfr[nb] = __builtin_amdgcn_mfma_f32_16x16x32_bf16(aq[ks], bk, sfr[nb], 0, 0, 0);
        }
      if (kt < qt) {                         // interior tiles: no causal test
        for (int nb = 0; nb < 4; ++nb) {
          const float bb = kbias[l15 + 16 * nb];
          for (int i = 0; i < 4; ++i)
            Pl[w][quad * 4 + i][l15 + 16 * nb] = f2bf_fast(exp2f(sfr[nb][i] * c2 + bb));
        }
      } else {                               // boundary tile: add causal mask
        for (int nb = 0; nb < 4; ++nb) {
          const int tg = l15 + 16 * nb;
          const float bb = kbias[l15 + 16 * nb];
          for (int i = 0; i < 4; ++i) {
            const float bbi = (tg > 16 * w + quad * 4 + i) ? -1.0e38f : bb;
            Pl[w][quad * 4 + i][l15 + 16 * nb] = f2bf_fast(exp2f(sfr[nb][i] * c2 + bbi));
          }
        }
      }
      asm volatile("s_waitcnt lgkmcnt(0)" ::: "memory");  // own-wave Pl writes
      bf16x8 ap0 = *(const bf16x8*)&Pl[w][l15][quad * 8];
      bf16x8 ap1 = *(const bf16x8*)&Pl[w][l15][32 + quad * 8];
      for (int no = 0; no < 4; ++no) {
        bf16x8 bv0 = *(const bf16x8*)&VT[16 * no + l15][quad * 8];
        bf16x8 bv1 = *(const bf16x8*)&VT[16 * no + l15][32 + quad * 8];
        o[no] = __builtin_amdgcn_mfma_f32_16x16x32_bf16(ap0, bv0, o[no], 0, 0, 0);
        o[no] = __builtin_amdgcn_mfma_f32_16x16x32_bf16(ap1, bv1, o[no], 0, 0, 0);
      }
      lsum = __builtin_amdgcn_mfma_f32_16x16x32_bf16(ap0, ones, lsum, 0, 0, 0);
      lsum = __builtin_amdgcn_mfma_f32_16x16x32_bf16(ap1, ones, lsum, 0, 0, 0);
    }
    // epilogue: write partials; kh=0 also writes V rows for masked queries
    for (int i = 0; i < 4; ++i) {
      const int s = r0 + 16 * w + quad * 4 + i;
      const int qm = maskp[b * S_ + s];
      const size_t row = (size_t)(b * S_ + s) * E_ + hd * D_;
      if (kh == 0 && !qm) {
        for (int no = 0; no < 4; ++no) {
          const int d = l15 + 16 * no;
          ob[row + d] = vtb[(size_t)d * S_ + s];
        }
      }
      for (int no = 0; no < 4; ++no)
        PB[row + l15 + 16 * no] = f2bf(o[no][i]);
      if (l15 == 0)
        LB[bh * S_ + s] = lsum[i];
    }
  }
}

// ---------------------------------------------------------------------------
// merge: ob[m][e] = (P0 + P1) / (l0 + l1) for unmasked rows
// ---------------------------------------------------------------------------
__global__ __launch_bounds__(256) void merge_kernel(
    const short* __restrict__ pb0, const short* __restrict__ pb1,
    const float* __restrict__ lb0, const float* __restrict__ lb1,
    const int* __restrict__ maskp, short* __restrict__ ob) {
  int idx = blockIdx.x * 256 + threadIdx.x;  // 8192*64 threads
  int m = idx >> 6, e = (idx & 63) * 8;
  if (!maskp[m]) return;                     // masked row: flash wrote V
  int b = m >> 11, s = m & (S_ - 1);
  int bh = b * 8 + (e >> 6);
  float l = lb0[bh * S_ + s] + lb1[bh * S_ + s];
  float inv = 1.f / l;
  bf16x8 p0 = *(const bf16x8*)&pb0[(size_t)m * E_ + e];
  bf16x8 p1 = *(const bf16x8*)&pb1[(size_t)m * E_ + e];
  bf16x8 r;
  for (int j = 0; j < 8; ++j)
    r[j] = f2bf((bf2f(p0[j]) + bf2f(p1[j])) * inv);
  *(bf16x8*)&ob[(size_t)m * E_ + e] = r;
}

extern "C" void kernel_launch(void* const* d_in, const int* in_sizes, int n_in,
                              void* d_out, int out_size, void* d_ws, size_t ws_size,
                              hipStream_t stream) {
  const float* x    = (const float*)d_in[0];
  const int*   mask = (const int*)d_in[1];
  const float* Win  = (const float*)d_in[2];
  const float* Wout = (const float*)d_in[3];
  float* out = (float*)d_out;

  short* Xb    = (short*)d_ws;               // 8192*512
  short* Winb  = Xb + 8192 * 512;            // 1536*512
  short* Woutb = Winb + 1536 * 512;          // 512*512
  short* qb    = Woutb + 512 * 512;          // 32*2048*64 each
  short* kb    = qb + 32 * 2048 * 64;
  short* vbT   = kb + 32 * 2048 * 64;        // [bh][d][s] transposed
  short* ob    = vbT + 32 * 2048 * 64;       // 8192*512
  short* pb0   = ob + 8192 * 512;            // partial O, half 0 (bf16)
  short* pb1   = pb0 + 8192 * 512;           // partial O, half 1
  float* lb0   = (float*)(pb1 + 8192 * 512); // lsum partials [32][2048]
  float* lb1   = lb0 + 32 * 2048;            // total ws ~61.3 MB

  cvt_all<<<5120, 256, 0, stream>>>(x, Win, Wout, Xb, Winb, Woutb);
  gemm_qkv_mfma<<<dim3(64, 12), 256, 0, stream>>>(Xb, Winb, qb, kb, vbT);
  flash_mfma<<<1024, 256, 0, stream>>>(qb, kb, vbT, mask, pb0, pb1, lb0, lb1, ob);
  merge_kernel<<<2048, 256, 0, stream>>>(pb0, pb1, lb0, lb1, mask, ob);
  gemm_out_mfma<<<dim3(64, 4), 256, 0, stream>>>(ob, Woutb, out);
}

// Round 14
// 262.200 us; speedup vs baseline: 1.0326x; 1.0132x over previous
//
#include <hip/hip_runtime.h>
#include <math.h>

// Problem constants
#define B_ 4
#define S_ 2048
#define E_ 512
#define H_ 8
#define D_ 64

typedef short bf16x8 __attribute__((ext_vector_type(8)));
typedef float f32x4 __attribute__((ext_vector_type(4)));

__device__ inline short f2bf(float f) {  // fp32 -> bf16 bits, RNE
  union { float f; unsigned u; } v; v.f = f;
  unsigned r = v.u + 0x7FFF + ((v.u >> 16) & 1);
  return (short)(r >> 16);
}
__device__ inline short f2bf_fast(float f) {  // round-half-up (P matrix only)
  union { float f; unsigned u; } v; v.f = f;
  return (short)((v.u + 0x8000u) >> 16);
}
__device__ inline float bf2f(short s) {
  union { unsigned u; float f; } v; v.u = ((unsigned)(unsigned short)s) << 16;
  return v.f;
}

// ---------------------------------------------------------------------------
// fused fp32->bf16 convert for X, W_in, W_out in ONE launch (block ranges)
// ---------------------------------------------------------------------------
__global__ __launch_bounds__(256) void cvt_all(
    const float* __restrict__ x, const float* __restrict__ win,
    const float* __restrict__ wout, short* __restrict__ xb,
    short* __restrict__ winb, short* __restrict__ woutb) {
  int bid = blockIdx.x;
  const float* src; short* dst; int i;
  if (bid < 4096)      { src = x;    dst = xb;    i = bid * 256 + threadIdx.x; }
  else if (bid < 4864) { src = win;  dst = winb;  i = (bid - 4096) * 256 + threadIdx.x; }
  else                 { src = wout; dst = woutb; i = (bid - 4864) * 256 + threadIdx.x; }
  float4 f = ((const float4*)src)[i];
  short4 o;
  o.x = f2bf(f.x); o.y = f2bf(f.y); o.z = f2bf(f.z); o.w = f2bf(f.w);
  ((short4*)dst)[i] = o;
}

// ---------------------------------------------------------------------------
// MFMA GEMM 128x128 tile, BK=32, 4 waves (2x2), single-barrier register
// double-buffer staging. RoPE epilogue uses VALUE-returning __sinf/__cosf:
// __sincosf's pointer outs forced sn/cs to scratch -> 64 calls/thread
// re-dirtied scratch lines evicted by streaming reads = ~650 MB HBM writes
// (r12/r13 regression, falsified the staging theories). q,k stored
// [bh][s][d]; V TRANSPOSED [bh][d][s].
// ---------------------------------------------------------------------------
__global__ __launch_bounds__(256) void gemm_qkv_mfma(
    const short* __restrict__ Xb,    // [8192][512] bf16
    const short* __restrict__ Wb,    // [1536][512] bf16
    short* __restrict__ qb, short* __restrict__ kb, short* __restrict__ vbT) {
  __shared__ __align__(16) short As[2][128][40];
  __shared__ __align__(16) short Bs[2][128][40];
  const int tid = threadIdx.x;
  const int w = tid >> 6, lane = tid & 63;
  const int l15 = lane & 15, quad = lane >> 4;
  const int wm = w & 1, wn = w >> 1;
  const int m0 = blockIdx.x * 128;
  const int n0 = blockIdx.y * 128;
  // staging coords: thread covers chunks tid and tid+256 (of 512 8-short chunks)
  const int r0s = tid >> 2,        k80 = (tid & 3) * 8;
  const int r1s = (tid + 256) >> 2, k81 = ((tid + 256) & 3) * 8;
  const short* gA0 = &Xb[(size_t)(m0 + r0s) * E_ + k80];
  const short* gA1 = &Xb[(size_t)(m0 + r1s) * E_ + k81];
  const short* gB0 = &Wb[(size_t)(n0 + r0s) * E_ + k80];
  const short* gB1 = &Wb[(size_t)(n0 + r1s) * E_ + k81];
  f32x4 acc[4][4];
  for (int mt = 0; mt < 4; ++mt)
    for (int nt = 0; nt < 4; ++nt) acc[mt][nt] = (f32x4){0.f, 0.f, 0.f, 0.f};

  // prologue: stage K-slab 0 into buf 0
  bf16x8 ra0 = *(const bf16x8*)gA0;
  bf16x8 ra1 = *(const bf16x8*)gA1;
  bf16x8 rb0 = *(const bf16x8*)gB0;
  bf16x8 rb1 = *(const bf16x8*)gB1;
  *(bf16x8*)&As[0][r0s][k80] = ra0;
  *(bf16x8*)&As[0][r1s][k81] = ra1;
  *(bf16x8*)&Bs[0][r0s][k80] = rb0;
  *(bf16x8*)&Bs[0][r1s][k81] = rb1;
  __syncthreads();

  for (int kt = 0; kt < 16; ++kt) {
    const int cur = kt & 1;
    if (kt < 15) {                         // issue next slab's loads early
      const int k0 = (kt + 1) * 32;
      ra0 = *(const bf16x8*)(gA0 + k0);
      ra1 = *(const bf16x8*)(gA1 + k0);
      rb0 = *(const bf16x8*)(gB0 + k0);
      rb1 = *(const bf16x8*)(gB1 + k0);
    }
    bf16x8 a[4], bfr[4];
    for (int mt = 0; mt < 4; ++mt)
      a[mt] = *(const bf16x8*)&As[cur][wm * 64 + mt * 16 + l15][quad * 8];
    for (int nt = 0; nt < 4; ++nt)
      bfr[nt] = *(const bf16x8*)&Bs[cur][wn * 64 + nt * 16 + l15][quad * 8];
    for (int mt = 0; mt < 4; ++mt)
      for (int nt = 0; nt < 4; ++nt)
        acc[mt][nt] = __builtin_amdgcn_mfma_f32_16x16x32_bf16(a[mt], bfr[nt], acc[mt][nt], 0, 0, 0);
    if (kt < 15) {                         // write to other buffer (its readers
      const int nxt = cur ^ 1;             // finished at the previous barrier)
      *(bf16x8*)&As[nxt][r0s][k80] = ra0;
      *(bf16x8*)&As[nxt][r1s][k81] = ra1;
      *(bf16x8*)&Bs[nxt][r0s][k80] = rb0;
      *(bf16x8*)&Bs[nxt][r1s][k81] = rb1;
    }
    __syncthreads();
  }
  const int t3 = n0 >> 9;                  // uniform per block: 0=q 1=k 2=v
  for (int nt = 0; nt < 4; ++nt) {
    const int n = n0 + wn * 64 + nt * 16 + l15;
    const int h = (n >> 6) & 7;
    const int d = n & 63;
    const bool dorope = (t3 < 2) && (d < 32);
    const float sgn = (d & 1) ? 1.f : -1.f;
    const float fr = dorope ? powf(10000.f, -(float)(2 * (d >> 1)) * (1.f / 32.f)) : 0.f;
    for (int mt = 0; mt < 4; ++mt) {
      for (int i = 0; i < 4; ++i) {
        const int m = m0 + wm * 64 + mt * 16 + quad * 4 + i;
        const int b = m >> 11, s = m & (S_ - 1);
        float val = acc[mt][nt][i];
        float pv = __shfl_xor(val, 1, 64);
        float outv = val;
        if (dorope) {
          float ang = (float)s * fr;
          float sn = __sinf(ang);          // value-returning: no scratch
          float cs = __cosf(ang);
          outv = val * cs + pv * sgn * sn;
        }
        if (t3 == 2)
          vbT[((size_t)(b * 8 + h) * D_ + d) * S_ + s] = f2bf(outv);
        else {
          short* dst = (t3 == 0) ? qb : kb;
          dst[(((size_t)(b * 8 + h)) * S_ + s) * D_ + d] = f2bf(outv);
        }
      }
    }
  }
}

// ---------------------------------------------------------------------------
// gemm_out: out = ob @ Woutb^T, fp32 output; same dbuf staging
// ---------------------------------------------------------------------------
__global__ __launch_bounds__(256) void gemm_out_mfma(
    const short* __restrict__ Ab, const short* __restrict__ Wb,
    float* __restrict__ out) {
  __shared__ __align__(16) short As[2][128][40];
  __shared__ __align__(16) short Bs[2][128][40];
  const int tid = threadIdx.x;
  const int w = tid >> 6, lane = tid & 63;
  const int l15 = lane & 15, quad = lane >> 4;
  const int wm = w & 1, wn = w >> 1;
  const int m0 = blockIdx.x * 128;
  const int n0 = blockIdx.y * 128;
  const int r0s = tid >> 2,        k80 = (tid & 3) * 8;
  const int r1s = (tid + 256) >> 2, k81 = ((tid + 256) & 3) * 8;
  const short* gA0 = &Ab[(size_t)(m0 + r0s) * E_ + k80];
  const short* gA1 = &Ab[(size_t)(m0 + r1s) * E_ + k81];
  const short* gB0 = &Wb[(size_t)(n0 + r0s) * E_ + k80];
  const short* gB1 = &Wb[(size_t)(n0 + r1s) * E_ + k81];
  f32x4 acc[4][4];
  for (int mt = 0; mt < 4; ++mt)
    for (int nt = 0; nt < 4; ++nt) acc[mt][nt] = (f32x4){0.f, 0.f, 0.f, 0.f};

  bf16x8 ra0 = *(const bf16x8*)gA0;
  bf16x8 ra1 = *(const bf16x8*)gA1;
  bf16x8 rb0 = *(const bf16x8*)gB0;
  bf16x8 rb1 = *(const bf16x8*)gB1;
  *(bf16x8*)&As[0][r0s][k80] = ra0;
  *(bf16x8*)&As[0][r1s][k81] = ra1;
  *(bf16x8*)&Bs[0][r0s][k80] = rb0;
  *(bf16x8*)&Bs[0][r1s][k81] = rb1;
  __syncthreads();

  for (int kt = 0; kt < 16; ++kt) {
    const int cur = kt & 1;
    if (kt < 15) {
      const int k0 = (kt + 1) * 32;
      ra0 = *(const bf16x8*)(gA0 + k0);
      ra1 = *(const bf16x8*)(gA1 + k0);
      rb0 = *(const bf16x8*)(gB0 + k0);
      rb1 = *(const bf16x8*)(gB1 + k0);
    }
    bf16x8 a[4], bfr[4];
    for (int mt = 0; mt < 4; ++mt)
      a[mt] = *(const bf16x8*)&As[cur][wm * 64 + mt * 16 + l15][quad * 8];
    for (int nt = 0; nt < 4; ++nt)
      bfr[nt] = *(const bf16x8*)&Bs[cur][wn * 64 + nt * 16 + l15][quad * 8];
    for (int mt = 0; mt < 4; ++mt)
      for (int nt = 0; nt < 4; ++nt)
        acc[mt][nt] = __builtin_amdgcn_mfma_f32_16x16x32_bf16(a[mt], bfr[nt], acc[mt][nt], 0, 0, 0);
    if (kt < 15) {
      const int nxt = cur ^ 1;
      *(bf16x8*)&As[nxt][r0s][k80] = ra0;
      *(bf16x8*)&As[nxt][r1s][k81] = ra1;
      *(bf16x8*)&Bs[nxt][r0s][k80] = rb0;
      *(bf16x8*)&Bs[nxt][r1s][k81] = rb1;
    }
    __syncthreads();
  }
  for (int mt = 0; mt < 4; ++mt)
    for (int nt = 0; nt < 4; ++nt) {
      const int n = n0 + wn * 64 + nt * 16 + l15;
      for (int i = 0; i < 4; ++i) {
        const int m = m0 + wm * 64 + mt * 16 + quad * 4 + i;
        out[(size_t)m * E_ + n] = acc[mt][nt][i];
      }
    }
}

// ---------------------------------------------------------------------------
// Flash attention, MFMA, static-max softmax, SPLIT-K (unchanged from r11).
// ---------------------------------------------------------------------------
__global__ __launch_bounds__(256) void flash_mfma(
    const short* __restrict__ qb, const short* __restrict__ kb,
    const short* __restrict__ vbT, const int* __restrict__ maskp,
    short* __restrict__ pb0, short* __restrict__ pb1,
    float* __restrict__ lb0, float* __restrict__ lb1,
    short* __restrict__ ob) {
  __shared__ __align__(16) short Ks[64][72];
  __shared__ __align__(16) short VT[64][72];
  __shared__ __align__(16) short Pl[4][16][72];
  __shared__ float kbias[64];
  const int tid = threadIdx.x;
  const int w = tid >> 6, lane = tid & 63;
  const int l15 = lane & 15, quad = lane >> 4;
  const int bid = blockIdx.x;
  const int u = bid & 7, v = bid >> 3;       // u -> XCD under id&7 model
  const int bh = (u << 2) | (v & 3);         // 4 bh per XCD
  const int w2 = v >> 2;                     // 0..31
  const int pair = w2 & 15;                  // q-tile pair id
  const int kh = w2 >> 4;                    // split half: 0 or 1
  const int b = bh >> 3, hd = bh & 7;
  const short* qbase = qb + (size_t)bh * S_ * D_;
  const short* kbase = kb + (size_t)bh * S_ * D_;
  const short* vtb   = vbT + (size_t)bh * D_ * S_;
  short* PB = kh ? pb1 : pb0;
  float* LB = kh ? lb1 : lb0;
  const float c2 = 0.1803368801f;            // 0.125 * log2(e)
  bf16x8 ones;
  for (int j = 0; j < 8; ++j) ones[j] = (short)0x3F80;  // bf16 1.0

  for (int seg = 0; seg < 2; ++seg) {
    const int qt = (seg == 0) ? pair : 31 - pair;
    const int r0 = qt * 64;
    const int mid = (qt + 2) >> 1;           // ceil((qt+1)/2)
    const int lo = kh ? mid : 0;
    const int hi = kh ? (qt + 1) : mid;
    bf16x8 aq[2];
    {
      const short* qrow = qbase + (size_t)(r0 + 16 * w + l15) * D_;
      aq[0] = *(const bf16x8*)&qrow[quad * 8];
      aq[1] = *(const bf16x8*)&qrow[32 + quad * 8];
    }
    f32x4 o[4], lsum;
    for (int no = 0; no < 4; ++no) o[no] = (f32x4){0.f, 0.f, 0.f, 0.f};
    lsum = (f32x4){0.f, 0.f, 0.f, 0.f};

    for (int kt = lo; kt < hi; ++kt) {
      const int t0 = kt * 64;
      __syncthreads();                       // prior tile fully consumed
      for (int l = 0; l < 2; ++l) {
        int idx = tid + 256 * l;
        int row = idx >> 3, ch = (idx & 7) * 8;
        *(bf16x8*)&Ks[row][ch] = *(const bf16x8*)(kbase + (size_t)(t0 + row) * D_ + ch);
        *(bf16x8*)&VT[row][ch] = *(const bf16x8*)(vtb + (size_t)row * S_ + t0 + ch);
      }
      if (tid < 64)
        kbias[tid] = maskp[b * S_ + t0 + tid] ? -23.08312f : -1.0e38f;
      __syncthreads();
      f32x4 sfr[4];
      for (int nb = 0; nb < 4; ++nb) sfr[nb] = (f32x4){0.f, 0.f, 0.f, 0.f};
      for (int nb = 0; nb < 4; ++nb)
        for (int ks = 0; ks < 2; ++ks) {
          bf16x8 bk = *(const bf16x8*)&Ks[l15 + 16 * nb][32 * ks + quad * 8];
          sfr[nb] = __builtin_amdgcn_mfma_f32_16x16x32_bf16(aq[ks], bk, sfr[nb], 0, 0, 0);
        }
      if (kt < qt) {                         // interior tiles: no causal test
        for (int nb = 0; nb < 4; ++nb) {
          const float bb = kbias[l15 + 16 * nb];
          for (int i = 0; i < 4; ++i)
            Pl[w][quad * 4 + i][l15 + 16 * nb] = f2bf_fast(exp2f(sfr[nb][i] * c2 + bb));
        }
      } else {                               // boundary tile: add causal mask
        for (int nb = 0; nb < 4; ++nb) {
          const int tg = l15 + 16 * nb;
          const float bb = kbias[l15 + 16 * nb];
          for (int i = 0; i < 4; ++i) {
            const float bbi = (tg > 16 * w + quad * 4 + i) ? -1.0e38f : bb;
            Pl[w][quad * 4 + i][l15 + 16 * nb] = f2bf_fast(exp2f(sfr[nb][i] * c2 + bbi));
          }
        }
      }
      asm volatile("s_waitcnt lgkmcnt(0)" ::: "memory");  // own-wave Pl writes
      bf16x8 ap0 = *(const bf16x8*)&Pl[w][l15][quad * 8];
      bf16x8 ap1 = *(const bf16x8*)&Pl[w][l15][32 + quad * 8];
      for (int no = 0; no < 4; ++no) {
        bf16x8 bv0 = *(const bf16x8*)&VT[16 * no + l15][quad * 8];
        bf16x8 bv1 = *(const bf16x8*)&VT[16 * no + l15][32 + quad * 8];
        o[no] = __builtin_amdgcn_mfma_f32_16x16x32_bf16(ap0, bv0, o[no], 0, 0, 0);
        o[no] = __builtin_amdgcn_mfma_f32_16x16x32_bf16(ap1, bv1, o[no], 0, 0, 0);
      }
      lsum = __builtin_amdgcn_mfma_f32_16x16x32_bf16(ap0, ones, lsum, 0, 0, 0);
      lsum = __builtin_amdgcn_mfma_f32_16x16x32_bf16(ap1, ones, lsum, 0, 0, 0);
    }
    // epilogue: write partials; kh=0 also writes V rows for masked queries
    for (int i = 0; i < 4; ++i) {
      const int s = r0 + 16 * w + quad * 4 + i;
      const int qm = maskp[b * S_ + s];
      const size_t row = (size_t)(b * S_ + s) * E_ + hd * D_;
      if (kh == 0 && !qm) {
        for (int no = 0; no < 4; ++no) {
          const int d = l15 + 16 * no;
          ob[row + d] = vtb[(size_t)d * S_ + s];
        }
      }
      for (int no = 0; no < 4; ++no)
        PB[row + l15 + 16 * no] = f2bf(o[no][i]);
      if (l15 == 0)
        LB[bh * S_ + s] = lsum[i];
    }
  }
}

// ---------------------------------------------------------------------------
// merge: ob[m][e] = (P0 + P1) / (l0 + l1) for unmasked rows
// ---------------------------------------------------------------------------
__global__ __launch_bounds__(256) void merge_kernel(
    const short* __restrict__ pb0, const short* __restrict__ pb1,
    const float* __restrict__ lb0, const float* __restrict__ lb1,
    const int* __restrict__ maskp, short* __restrict__ ob) {
  int idx = blockIdx.x * 256 + threadIdx.x;  // 8192*64 threads
  int m = idx >> 6, e = (idx & 63) * 8;
  if (!maskp[m]) return;                     // masked row: flash wrote V
  int b = m >> 11, s = m & (S_ - 1);
  int bh = b * 8 + (e >> 6);
  float l = lb0[bh * S_ + s] + lb1[bh * S_ + s];
  float inv = 1.f / l;
  bf16x8 p0 = *(const bf16x8*)&pb0[(size_t)m * E_ + e];
  bf16x8 p1 = *(const bf16x8*)&pb1[(size_t)m * E_ + e];
  bf16x8 r;
  for (int j = 0; j < 8; ++j)
    r[j] = f2bf((bf2f(p0[j]) + bf2f(p1[j])) * inv);
  *(bf16x8*)&ob[(size_t)m * E_ + e] = r;
}

extern "C" void kernel_launch(void* const* d_in, const int* in_sizes, int n_in,
                              void* d_out, int out_size, void* d_ws, size_t ws_size,
                              hipStream_t stream) {
  const float* x    = (const float*)d_in[0];
  const int*   mask = (const int*)d_in[1];
  const float* Win  = (const float*)d_in[2];
  const float* Wout = (const float*)d_in[3];
  float* out = (float*)d_out;

  short* Xb    = (short*)d_ws;               // 8192*512
  short* Winb  = Xb + 8192 * 512;            // 1536*512
  short* Woutb = Winb + 1536 * 512;          // 512*512
  short* qb    = Woutb + 512 * 512;          // 32*2048*64 each
  short* kb    = qb + 32 * 2048 * 64;
  short* vbT   = kb + 32 * 2048 * 64;        // [bh][d][s] transposed
  short* ob    = vbT + 32 * 2048 * 64;       // 8192*512
  short* pb0   = ob + 8192 * 512;            // partial O, half 0 (bf16)
  short* pb1   = pb0 + 8192 * 512;           // partial O, half 1
  float* lb0   = (float*)(pb1 + 8192 * 512); // lsum partials [32][2048]
  float* lb1   = lb0 + 32 * 2048;            // total ws ~61.3 MB

  cvt_all<<<5120, 256, 0, stream>>>(x, Win, Wout, Xb, Winb, Woutb);
  gemm_qkv_mfma<<<dim3(64, 12), 256, 0, stream>>>(Xb, Winb, qb, kb, vbT);
  flash_mfma<<<1024, 256, 0, stream>>>(qb, kb, vbT, mask, pb0, pb1, lb0, lb1, ob);
  merge_kernel<<<2048, 256, 0, stream>>>(pb0, pb1, lb0, lb1, mask, ob);
  gemm_out_mfma<<<dim3(64, 4), 256, 0, stream>>>(ob, Woutb, out);
}

// Round 15
// 175.472 us; speedup vs baseline: 1.5430x; 1.4943x over previous
//
#include <hip/hip_runtime.h>
#include <math.h>

// Problem constants
#define B_ 4
#define S_ 2048
#define E_ 512
#define H_ 8
#define D_ 64

typedef short bf16x8 __attribute__((ext_vector_type(8)));
typedef float f32x4 __attribute__((ext_vector_type(4)));

__device__ inline short f2bf(float f) {  // fp32 -> bf16 bits, RNE
  union { float f; unsigned u; } v; v.f = f;
  unsigned r = v.u + 0x7FFF + ((v.u >> 16) & 1);
  return (short)(r >> 16);
}
__device__ inline short f2bf_fast(float f) {  // round-half-up (P matrix only)
  union { float f; unsigned u; } v; v.f = f;
  return (short)((v.u + 0x8000u) >> 16);
}
__device__ inline float bf2f(short s) {
  union { unsigned u; float f; } v; v.u = ((unsigned)(unsigned short)s) << 16;
  return v.f;
}

// ---------------------------------------------------------------------------
// fused fp32->bf16 convert for X, W_in, W_out in ONE launch (block ranges)
// (independent kernel — kept; GEMM regression was in-kernel spills, not cvt)
// ---------------------------------------------------------------------------
__global__ __launch_bounds__(256) void cvt_all(
    const float* __restrict__ x, const float* __restrict__ win,
    const float* __restrict__ wout, short* __restrict__ xb,
    short* __restrict__ winb, short* __restrict__ woutb) {
  int bid = blockIdx.x;
  const float* src; short* dst; int i;
  if (bid < 4096)      { src = x;    dst = xb;    i = bid * 256 + threadIdx.x; }
  else if (bid < 4864) { src = win;  dst = winb;  i = (bid - 4096) * 256 + threadIdx.x; }
  else                 { src = wout; dst = woutb; i = (bid - 4864) * 256 + threadIdx.x; }
  float4 f = ((const float4*)src)[i];
  short4 o;
  o.x = f2bf(f.x); o.y = f2bf(f.y); o.z = f2bf(f.z); o.w = f2bf(f.w);
  ((short4*)dst)[i] = o;
}

// ---------------------------------------------------------------------------
// MFMA GEMM 128x128 tile, BK=32, 4 waves (2x2). VERBATIM bench-r11 version
// (53 us, WRITE 25 MB, VGPR 104). DO NOT restructure the staging loop:
// r12 (async16), r13/r14 (reg-dbuf + precomputed pointer set) all made the
// allocator spill the f32x4 acc[4][4] to scratch (VGPR_Count dropped to 72,
// WRITE_SIZE 650-750 MB, 133+ us). Two-barrier staging, recomputed
// addresses, sincosf/powf epilogue — all proven on HW.
// q,k stored [bh][s][d]; V stored TRANSPOSED [bh][d][s].
// ---------------------------------------------------------------------------
__global__ __launch_bounds__(256) void gemm_qkv_mfma(
    const short* __restrict__ Xb,    // [8192][512] bf16
    const short* __restrict__ Wb,    // [1536][512] bf16
    short* __restrict__ qb, short* __restrict__ kb, short* __restrict__ vbT) {
  __shared__ __align__(16) short As[128][40];
  __shared__ __align__(16) short Bs[128][40];
  const int tid = threadIdx.x;
  const int w = tid >> 6, lane = tid & 63;
  const int l15 = lane & 15, quad = lane >> 4;
  const int wm = w & 1, wn = w >> 1;
  const int m0 = blockIdx.x * 128;
  const int n0 = blockIdx.y * 128;
  f32x4 acc[4][4];
  for (int mt = 0; mt < 4; ++mt)
    for (int nt = 0; nt < 4; ++nt) acc[mt][nt] = (f32x4){0.f, 0.f, 0.f, 0.f};

  for (int k0 = 0; k0 < E_; k0 += 32) {
    __syncthreads();
    for (int l = 0; l < 2; ++l) {
      int c = tid + 256 * l;
      int row = c >> 2, k8 = (c & 3) * 8;
      *(bf16x8*)&As[row][k8] = *(const bf16x8*)&Xb[(size_t)(m0 + row) * E_ + k0 + k8];
      *(bf16x8*)&Bs[row][k8] = *(const bf16x8*)&Wb[(size_t)(n0 + row) * E_ + k0 + k8];
    }
    __syncthreads();
    bf16x8 a[4], bfr[4];
    for (int mt = 0; mt < 4; ++mt)
      a[mt] = *(const bf16x8*)&As[wm * 64 + mt * 16 + l15][quad * 8];
    for (int nt = 0; nt < 4; ++nt)
      bfr[nt] = *(const bf16x8*)&Bs[wn * 64 + nt * 16 + l15][quad * 8];
    for (int mt = 0; mt < 4; ++mt)
      for (int nt = 0; nt < 4; ++nt)
        acc[mt][nt] = __builtin_amdgcn_mfma_f32_16x16x32_bf16(a[mt], bfr[nt], acc[mt][nt], 0, 0, 0);
  }
  const int t3 = n0 >> 9;                  // uniform per block: 0=q 1=k 2=v
  for (int nt = 0; nt < 4; ++nt) {
    const int n = n0 + wn * 64 + nt * 16 + l15;
    const int h = (n >> 6) & 7;
    const int d = n & 63;
    const bool dorope = (t3 < 2) && (d < 32);
    const float sgn = (d & 1) ? 1.f : -1.f;
    const float fr = dorope ? powf(10000.f, -(float)(2 * (d >> 1)) * (1.f / 32.f)) : 0.f;
    for (int mt = 0; mt < 4; ++mt) {
      for (int i = 0; i < 4; ++i) {
        const int m = m0 + wm * 64 + mt * 16 + quad * 4 + i;
        const int b = m >> 11, s = m & (S_ - 1);
        float val = acc[mt][nt][i];
        float pv = __shfl_xor(val, 1, 64);
        float outv = val;
        if (dorope) {
          float ang = (float)s * fr;
          float sn, cs;
          sincosf(ang, &sn, &cs);
          outv = val * cs + pv * sgn * sn;
        }
        if (t3 == 2)
          vbT[((size_t)(b * 8 + h) * D_ + d) * S_ + s] = f2bf(outv);
        else {
          short* dst = (t3 == 0) ? qb : kb;
          dst[(((size_t)(b * 8 + h)) * S_ + s) * D_ + d] = f2bf(outv);
        }
      }
    }
  }
}

// ---------------------------------------------------------------------------
// gemm_out: out = ob @ Woutb^T, fp32 output. VERBATIM bench-r11 version.
// ---------------------------------------------------------------------------
__global__ __launch_bounds__(256) void gemm_out_mfma(
    const short* __restrict__ Ab, const short* __restrict__ Wb,
    float* __restrict__ out) {
  __shared__ __align__(16) short As[128][40];
  __shared__ __align__(16) short Bs[128][40];
  const int tid = threadIdx.x;
  const int w = tid >> 6, lane = tid & 63;
  const int l15 = lane & 15, quad = lane >> 4;
  const int wm = w & 1, wn = w >> 1;
  const int m0 = blockIdx.x * 128;
  const int n0 = blockIdx.y * 128;
  f32x4 acc[4][4];
  for (int mt = 0; mt < 4; ++mt)
    for (int nt = 0; nt < 4; ++nt) acc[mt][nt] = (f32x4){0.f, 0.f, 0.f, 0.f};

  for (int k0 = 0; k0 < E_; k0 += 32) {
    __syncthreads();
    for (int l = 0; l < 2; ++l) {
      int c = tid + 256 * l;
      int row = c >> 2, k8 = (c & 3) * 8;
      *(bf16x8*)&As[row][k8] = *(const bf16x8*)&Ab[(size_t)(m0 + row) * E_ + k0 + k8];
      *(bf16x8*)&Bs[row][k8] = *(const bf16x8*)&Wb[(size_t)(n0 + row) * E_ + k0 + k8];
    }
    __syncthreads();
    bf16x8 a[4], bfr[4];
    for (int mt = 0; mt < 4; ++mt)
      a[mt] = *(const bf16x8*)&As[wm * 64 + mt * 16 + l15][quad * 8];
    for (int nt = 0; nt < 4; ++nt)
      bfr[nt] = *(const bf16x8*)&Bs[wn * 64 + nt * 16 + l15][quad * 8];
    for (int mt = 0; mt < 4; ++mt)
      for (int nt = 0; nt < 4; ++nt)
        acc[mt][nt] = __builtin_amdgcn_mfma_f32_16x16x32_bf16(a[mt], bfr[nt], acc[mt][nt], 0, 0, 0);
  }
  for (int mt = 0; mt < 4; ++mt)
    for (int nt = 0; nt < 4; ++nt) {
      const int n = n0 + wn * 64 + nt * 16 + l15;
      for (int i = 0; i < 4; ++i) {
        const int m = m0 + wm * 64 + mt * 16 + quad * 4 + i;
        out[(size_t)m * E_ + n] = acc[mt][nt][i];
      }
    }
}

// ---------------------------------------------------------------------------
// Flash attention, MFMA, static-max softmax, SPLIT-K (unchanged; proven).
// ---------------------------------------------------------------------------
__global__ __launch_bounds__(256) void flash_mfma(
    const short* __restrict__ qb, const short* __restrict__ kb,
    const short* __restrict__ vbT, const int* __restrict__ maskp,
    short* __restrict__ pb0, short* __restrict__ pb1,
    float* __restrict__ lb0, float* __restrict__ lb1,
    short* __restrict__ ob) {
  __shared__ __align__(16) short Ks[64][72];
  __shared__ __align__(16) short VT[64][72];
  __shared__ __align__(16) short Pl[4][16][72];
  __shared__ float kbias[64];
  const int tid = threadIdx.x;
  const int w = tid >> 6, lane = tid & 63;
  const int l15 = lane & 15, quad = lane >> 4;
  const int bid = blockIdx.x;
  const int u = bid & 7, v = bid >> 3;       // u -> XCD under id&7 model
  const int bh = (u << 2) | (v & 3);         // 4 bh per XCD
  const int w2 = v >> 2;                     // 0..31
  const int pair = w2 & 15;                  // q-tile pair id
  const int kh = w2 >> 4;                    // split half: 0 or 1
  const int b = bh >> 3, hd = bh & 7;
  const short* qbase = qb + (size_t)bh * S_ * D_;
  const short* kbase = kb + (size_t)bh * S_ * D_;
  const short* vtb   = vbT + (size_t)bh * D_ * S_;
  short* PB = kh ? pb1 : pb0;
  float* LB = kh ? lb1 : lb0;
  const float c2 = 0.1803368801f;            // 0.125 * log2(e)
  bf16x8 ones;
  for (int j = 0; j < 8; ++j) ones[j] = (short)0x3F80;  // bf16 1.0

  for (int seg = 0; seg < 2; ++seg) {
    const int qt = (seg == 0) ? pair : 31 - pair;
    const int r0 = qt * 64;
    const int mid = (qt + 2) >> 1;           // ceil((qt+1)/2)
    const int lo = kh ? mid : 0;
    const int hi = kh ? (qt + 1) : mid;
    bf16x8 aq[2];
    {
      const short* qrow = qbase + (size_t)(r0 + 16 * w + l15) * D_;
      aq[0] = *(const bf16x8*)&qrow[quad * 8];
      aq[1] = *(const bf16x8*)&qrow[32 + quad * 8];
    }
    f32x4 o[4], lsum;
    for (int no = 0; no < 4; ++no) o[no] = (f32x4){0.f, 0.f, 0.f, 0.f};
    lsum = (f32x4){0.f, 0.f, 0.f, 0.f};

    for (int kt = lo; kt < hi; ++kt) {
      const int t0 = kt * 64;
      __syncthreads();                       // prior tile fully consumed
      for (int l = 0; l < 2; ++l) {
        int idx = tid + 256 * l;
        int row = idx >> 3, ch = (idx & 7) * 8;
        *(bf16x8*)&Ks[row][ch] = *(const bf16x8*)(kbase + (size_t)(t0 + row) * D_ + ch);
        *(bf16x8*)&VT[row][ch] = *(const bf16x8*)(vtb + (size_t)row * S_ + t0 + ch);
      }
      if (tid < 64)
        kbias[tid] = maskp[b * S_ + t0 + tid] ? -23.08312f : -1.0e38f;
      __syncthreads();
      f32x4 sfr[4];
      for (int nb = 0; nb < 4; ++nb) sfr[nb] = (f32x4){0.f, 0.f, 0.f, 0.f};
      for (int nb = 0; nb < 4; ++nb)
        for (int ks = 0; ks < 2; ++ks) {
          bf16x8 bk = *(const bf16x8*)&Ks[l15 + 16 * nb][32 * ks + quad * 8];
          sfr[nb] = __builtin_amdgcn_mfma_f32_16x16x32_bf16(aq[ks], bk, sfr[nb], 0, 0, 0);
        }
      if (kt < qt) {                         // interior tiles: no causal test
        for (int nb = 0; nb < 4; ++nb) {
          const float bb = kbias[l15 + 16 * nb];
          for (int i = 0; i < 4; ++i)
            Pl[w][quad * 4 + i][l15 + 16 * nb] = f2bf_fast(exp2f(sfr[nb][i] * c2 + bb));
        }
      } else {                               // boundary tile: add causal mask
        for (int nb = 0; nb < 4; ++nb) {
          const int tg = l15 + 16 * nb;
          const float bb = kbias[l15 + 16 * nb];
          for (int i = 0; i < 4; ++i) {
            const float bbi = (tg > 16 * w + quad * 4 + i) ? -1.0e38f : bb;
            Pl[w][quad * 4 + i][l15 + 16 * nb] = f2bf_fast(exp2f(sfr[nb][i] * c2 + bbi));
          }
        }
      }
      asm volatile("s_waitcnt lgkmcnt(0)" ::: "memory");  // own-wave Pl writes
      bf16x8 ap0 = *(const bf16x8*)&Pl[w][l15][quad * 8];
      bf16x8 ap1 = *(const bf16x8*)&Pl[w][l15][32 + quad * 8];
      for (int no = 0; no < 4; ++no) {
        bf16x8 bv0 = *(const bf16x8*)&VT[16 * no + l15][quad * 8];
        bf16x8 bv1 = *(const bf16x8*)&VT[16 * no + l15][32 + quad * 8];
        o[no] = __builtin_amdgcn_mfma_f32_16x16x32_bf16(ap0, bv0, o[no], 0, 0, 0);
        o[no] = __builtin_amdgcn_mfma_f32_16x16x32_bf16(ap1, bv1, o[no], 0, 0, 0);
      }
      lsum = __builtin_amdgcn_mfma_f32_16x16x32_bf16(ap0, ones, lsum, 0, 0, 0);
      lsum = __builtin_amdgcn_mfma_f32_16x16x32_bf16(ap1, ones, lsum, 0, 0, 0);
    }
    // epilogue: write partials; kh=0 also writes V rows for masked queries
    for (int i = 0; i < 4; ++i) {
      const int s = r0 + 16 * w + quad * 4 + i;
      const int qm = maskp[b * S_ + s];
      const size_t row = (size_t)(b * S_ + s) * E_ + hd * D_;
      if (kh == 0 && !qm) {
        for (int no = 0; no < 4; ++no) {
          const int d = l15 + 16 * no;
          ob[row + d] = vtb[(size_t)d * S_ + s];
        }
      }
      for (int no = 0; no < 4; ++no)
        PB[row + l15 + 16 * no] = f2bf(o[no][i]);
      if (l15 == 0)
        LB[bh * S_ + s] = lsum[i];
    }
  }
}

// ---------------------------------------------------------------------------
// merge: ob[m][e] = (P0 + P1) / (l0 + l1) for unmasked rows
// ---------------------------------------------------------------------------
__global__ __launch_bounds__(256) void merge_kernel(
    const short* __restrict__ pb0, const short* __restrict__ pb1,
    const float* __restrict__ lb0, const float* __restrict__ lb1,
    const int* __restrict__ maskp, short* __restrict__ ob) {
  int idx = blockIdx.x * 256 + threadIdx.x;  // 8192*64 threads
  int m = idx >> 6, e = (idx & 63) * 8;
  if (!maskp[m]) return;                     // masked row: flash wrote V
  int b = m >> 11, s = m & (S_ - 1);
  int bh = b * 8 + (e >> 6);
  float l = lb0[bh * S_ + s] + lb1[bh * S_ + s];
  float inv = 1.f / l;
  bf16x8 p0 = *(const bf16x8*)&pb0[(size_t)m * E_ + e];
  bf16x8 p1 = *(const bf16x8*)&pb1[(size_t)m * E_ + e];
  bf16x8 r;
  for (int j = 0; j < 8; ++j)
    r[j] = f2bf((bf2f(p0[j]) + bf2f(p1[j])) * inv);
  *(bf16x8*)&ob[(size_t)m * E_ + e] = r;
}

extern "C" void kernel_launch(void* const* d_in, const int* in_sizes, int n_in,
                              void* d_out, int out_size, void* d_ws, size_t ws_size,
                              hipStream_t stream) {
  const float* x    = (const float*)d_in[0];
  const int*   mask = (const int*)d_in[1];
  const float* Win  = (const float*)d_in[2];
  const float* Wout = (const float*)d_in[3];
  float* out = (float*)d_out;

  short* Xb    = (short*)d_ws;               // 8192*512
  short* Winb  = Xb + 8192 * 512;            // 1536*512
  short* Woutb = Winb + 1536 * 512;          // 512*512
  short* qb    = Woutb + 512 * 512;          // 32*2048*64 each
  short* kb    = qb + 32 * 2048 * 64;
  short* vbT   = kb + 32 * 2048 * 64;        // [bh][d][s] transposed
  short* ob    = vbT + 32 * 2048 * 64;       // 8192*512
  short* pb0   = ob + 8192 * 512;            // partial O, half 0 (bf16)
  short* pb1   = pb0 + 8192 * 512;           // partial O, half 1
  float* lb0   = (float*)(pb1 + 8192 * 512); // lsum partials [32][2048]
  float* lb1   = lb0 + 32 * 2048;            // total ws ~61.3 MB

  cvt_all<<<5120, 256, 0, stream>>>(x, Win, Wout, Xb, Winb, Woutb);
  gemm_qkv_mfma<<<dim3(64, 12), 256, 0, stream>>>(Xb, Winb, qb, kb, vbT);
  flash_mfma<<<1024, 256, 0, stream>>>(qb, kb, vbT, mask, pb0, pb1, lb0, lb1, ob);
  merge_kernel<<<2048, 256, 0, stream>>>(pb0, pb1, lb0, lb1, mask, ob);
  gemm_out_mfma<<<dim3(64, 4), 256, 0, stream>>>(ob, Woutb, out);
}

// Round 16
// 171.334 us; speedup vs baseline: 1.5802x; 1.0241x over previous
//
#include <hip/hip_runtime.h>
#include <math.h>

// Problem constants
#define B_ 4
#define S_ 2048
#define E_ 512
#define H_ 8
#define D_ 64

typedef short bf16x8 __attribute__((ext_vector_type(8)));
typedef float f32x4 __attribute__((ext_vector_type(4)));

__device__ inline short f2bf(float f) {  // fp32 -> bf16 bits, RNE
  union { float f; unsigned u; } v; v.f = f;
  unsigned r = v.u + 0x7FFF + ((v.u >> 16) & 1);
  return (short)(r >> 16);
}
__device__ inline short f2bf_fast(float f) {  // round-half-up (P matrix only)
  union { float f; unsigned u; } v; v.f = f;
  return (short)((v.u + 0x8000u) >> 16);
}
__device__ inline float bf2f(short s) {
  union { unsigned u; float f; } v; v.u = ((unsigned)(unsigned short)s) << 16;
  return v.f;
}

// ---------------------------------------------------------------------------
// fused fp32->bf16 convert for X, W_in, W_out in ONE launch (block ranges)
// ---------------------------------------------------------------------------
__global__ __launch_bounds__(256) void cvt_all(
    const float* __restrict__ x, const float* __restrict__ win,
    const float* __restrict__ wout, short* __restrict__ xb,
    short* __restrict__ winb, short* __restrict__ woutb) {
  int bid = blockIdx.x;
  const float* src; short* dst; int i;
  if (bid < 4096)      { src = x;    dst = xb;    i = bid * 256 + threadIdx.x; }
  else if (bid < 4864) { src = win;  dst = winb;  i = (bid - 4096) * 256 + threadIdx.x; }
  else                 { src = wout; dst = woutb; i = (bid - 4864) * 256 + threadIdx.x; }
  float4 f = ((const float4*)src)[i];
  short4 o;
  o.x = f2bf(f.x); o.y = f2bf(f.y); o.z = f2bf(f.z); o.w = f2bf(f.w);
  ((short4*)dst)[i] = o;
}

// ---------------------------------------------------------------------------
// MFMA GEMM, 128x64 tile (was 128x128), BK=32, 4 waves (2x2: wave = 64x32).
// Grid 1536 blocks = 6/CU: the r15 counters showed the 2-barrier K-loop is
// per-block latency-bound (~14 us/block vs 0.9 us MFMA) with only 3
// blocks/CU — more co-resident blocks hide it via TLP (same cure as flash's
// split-K). Body shape is VERBATIM r11 (recomputed addresses, single LDS
// buffer, 2 barriers): r12-r14 proved ANY restructure (async16 / reg-dbuf /
// precomputed pointer sets) makes the allocator spill acc to scratch
// (WRITE_SIZE 25->650+ MB). Only constants changed here; acc shrinks 64->32
// VGPR. Epilogue fuses RoPE; q,k stored [bh][s][d]; V TRANSPOSED [bh][d][s].
// ---------------------------------------------------------------------------
__global__ __launch_bounds__(256) void gemm_qkv_mfma(
    const short* __restrict__ Xb,    // [8192][512] bf16
    const short* __restrict__ Wb,    // [1536][512] bf16
    short* __restrict__ qb, short* __restrict__ kb, short* __restrict__ vbT) {
  __shared__ __align__(16) short As[128][40];
  __shared__ __align__(16) short Bs[64][40];
  const int tid = threadIdx.x;
  const int w = tid >> 6, lane = tid & 63;
  const int l15 = lane & 15, quad = lane >> 4;
  const int wm = w & 1, wn = w >> 1;
  const int m0 = blockIdx.x * 128;
  const int n0 = blockIdx.y * 64;
  f32x4 acc[4][2];
  for (int mt = 0; mt < 4; ++mt)
    for (int nt = 0; nt < 2; ++nt) acc[mt][nt] = (f32x4){0.f, 0.f, 0.f, 0.f};

  for (int k0 = 0; k0 < E_; k0 += 32) {
    __syncthreads();
    for (int l = 0; l < 2; ++l) {        // A: 512 chunks of 8 shorts
      int c = tid + 256 * l;
      int row = c >> 2, k8 = (c & 3) * 8;
      *(bf16x8*)&As[row][k8] = *(const bf16x8*)&Xb[(size_t)(m0 + row) * E_ + k0 + k8];
    }
    {                                     // B: 256 chunks
      int row = tid >> 2, k8 = (tid & 3) * 8;
      *(bf16x8*)&Bs[row][k8] = *(const bf16x8*)&Wb[(size_t)(n0 + row) * E_ + k0 + k8];
    }
    __syncthreads();
    bf16x8 a[4], bfr[2];
    for (int mt = 0; mt < 4; ++mt)
      a[mt] = *(const bf16x8*)&As[wm * 64 + mt * 16 + l15][quad * 8];
    for (int nt = 0; nt < 2; ++nt)
      bfr[nt] = *(const bf16x8*)&Bs[wn * 32 + nt * 16 + l15][quad * 8];
    for (int mt = 0; mt < 4; ++mt)
      for (int nt = 0; nt < 2; ++nt)
        acc[mt][nt] = __builtin_amdgcn_mfma_f32_16x16x32_bf16(a[mt], bfr[nt], acc[mt][nt], 0, 0, 0);
  }
  const int t3 = n0 >> 9;                  // uniform per block: 0=q 1=k 2=v
  for (int nt = 0; nt < 2; ++nt) {
    const int n = n0 + wn * 32 + nt * 16 + l15;
    const int h = (n >> 6) & 7;
    const int d = n & 63;
    const bool dorope = (t3 < 2) && (d < 32);
    const float sgn = (d & 1) ? 1.f : -1.f;
    const float fr = dorope ? powf(10000.f, -(float)(2 * (d >> 1)) * (1.f / 32.f)) : 0.f;
    for (int mt = 0; mt < 4; ++mt) {
      for (int i = 0; i < 4; ++i) {
        const int m = m0 + wm * 64 + mt * 16 + quad * 4 + i;
        const int b = m >> 11, s = m & (S_ - 1);
        float val = acc[mt][nt][i];
        float pv = __shfl_xor(val, 1, 64);
        float outv = val;
        if (dorope) {
          float ang = (float)s * fr;
          float sn, cs;
          sincosf(ang, &sn, &cs);
          outv = val * cs + pv * sgn * sn;
        }
        if (t3 == 2)
          vbT[((size_t)(b * 8 + h) * D_ + d) * S_ + s] = f2bf(outv);
        else {
          short* dst = (t3 == 0) ? qb : kb;
          dst[(((size_t)(b * 8 + h)) * S_ + s) * D_ + d] = f2bf(outv);
        }
      }
    }
  }
}

// ---------------------------------------------------------------------------
// gemm_out: out = ob @ Woutb^T, fp32 output. Same 128x64 tiling (512 blocks).
// ---------------------------------------------------------------------------
__global__ __launch_bounds__(256) void gemm_out_mfma(
    const short* __restrict__ Ab, const short* __restrict__ Wb,
    float* __restrict__ out) {
  __shared__ __align__(16) short As[128][40];
  __shared__ __align__(16) short Bs[64][40];
  const int tid = threadIdx.x;
  const int w = tid >> 6, lane = tid & 63;
  const int l15 = lane & 15, quad = lane >> 4;
  const int wm = w & 1, wn = w >> 1;
  const int m0 = blockIdx.x * 128;
  const int n0 = blockIdx.y * 64;
  f32x4 acc[4][2];
  for (int mt = 0; mt < 4; ++mt)
    for (int nt = 0; nt < 2; ++nt) acc[mt][nt] = (f32x4){0.f, 0.f, 0.f, 0.f};

  for (int k0 = 0; k0 < E_; k0 += 32) {
    __syncthreads();
    for (int l = 0; l < 2; ++l) {
      int c = tid + 256 * l;
      int row = c >> 2, k8 = (c & 3) * 8;
      *(bf16x8*)&As[row][k8] = *(const bf16x8*)&Ab[(size_t)(m0 + row) * E_ + k0 + k8];
    }
    {
      int row = tid >> 2, k8 = (tid & 3) * 8;
      *(bf16x8*)&Bs[row][k8] = *(const bf16x8*)&Wb[(size_t)(n0 + row) * E_ + k0 + k8];
    }
    __syncthreads();
    bf16x8 a[4], bfr[2];
    for (int mt = 0; mt < 4; ++mt)
      a[mt] = *(const bf16x8*)&As[wm * 64 + mt * 16 + l15][quad * 8];
    for (int nt = 0; nt < 2; ++nt)
      bfr[nt] = *(const bf16x8*)&Bs[wn * 32 + nt * 16 + l15][quad * 8];
    for (int mt = 0; mt < 4; ++mt)
      for (int nt = 0; nt < 2; ++nt)
        acc[mt][nt] = __builtin_amdgcn_mfma_f32_16x16x32_bf16(a[mt], bfr[nt], acc[mt][nt], 0, 0, 0);
  }
  for (int mt = 0; mt < 4; ++mt)
    for (int nt = 0; nt < 2; ++nt) {
      const int n = n0 + wn * 32 + nt * 16 + l15;
      for (int i = 0; i < 4; ++i) {
        const int m = m0 + wm * 64 + mt * 16 + quad * 4 + i;
        out[(size_t)m * E_ + n] = acc[mt][nt][i];
      }
    }
}

// ---------------------------------------------------------------------------
// Flash attention, MFMA, static-max softmax, SPLIT-K (unchanged; proven).
// ---------------------------------------------------------------------------
__global__ __launch_bounds__(256) void flash_mfma(
    const short* __restrict__ qb, const short* __restrict__ kb,
    const short* __restrict__ vbT, const int* __restrict__ maskp,
    short* __restrict__ pb0, short* __restrict__ pb1,
    float* __restrict__ lb0, float* __restrict__ lb1,
    short* __restrict__ ob) {
  __shared__ __align__(16) short Ks[64][72];
  __shared__ __align__(16) short VT[64][72];
  __shared__ __align__(16) short Pl[4][16][72];
  __shared__ float kbias[64];
  const int tid = threadIdx.x;
  const int w = tid >> 6, lane = tid & 63;
  const int l15 = lane & 15, quad = lane >> 4;
  const int bid = blockIdx.x;
  const int u = bid & 7, v = bid >> 3;       // u -> XCD under id&7 model
  const int bh = (u << 2) | (v & 3);         // 4 bh per XCD
  const int w2 = v >> 2;                     // 0..31
  const int pair = w2 & 15;                  // q-tile pair id
  const int kh = w2 >> 4;                    // split half: 0 or 1
  const int b = bh >> 3, hd = bh & 7;
  const short* qbase = qb + (size_t)bh * S_ * D_;
  const short* kbase = kb + (size_t)bh * S_ * D_;
  const short* vtb   = vbT + (size_t)bh * D_ * S_;
  short* PB = kh ? pb1 : pb0;
  float* LB = kh ? lb1 : lb0;
  const float c2 = 0.1803368801f;            // 0.125 * log2(e)
  bf16x8 ones;
  for (int j = 0; j < 8; ++j) ones[j] = (short)0x3F80;  // bf16 1.0

  for (int seg = 0; seg < 2; ++seg) {
    const int qt = (seg == 0) ? pair : 31 - pair;
    const int r0 = qt * 64;
    const int mid = (qt + 2) >> 1;           // ceil((qt+1)/2)
    const int lo = kh ? mid : 0;
    const int hi = kh ? (qt + 1) : mid;
    bf16x8 aq[2];
    {
      const short* qrow = qbase + (size_t)(r0 + 16 * w + l15) * D_;
      aq[0] = *(const bf16x8*)&qrow[quad * 8];
      aq[1] = *(const bf16x8*)&qrow[32 + quad * 8];
    }
    f32x4 o[4], lsum;
    for (int no = 0; no < 4; ++no) o[no] = (f32x4){0.f, 0.f, 0.f, 0.f};
    lsum = (f32x4){0.f, 0.f, 0.f, 0.f};

    for (int kt = lo; kt < hi; ++kt) {
      const int t0 = kt * 64;
      __syncthreads();                       // prior tile fully consumed
      for (int l = 0; l < 2; ++l) {
        int idx = tid + 256 * l;
        int row = idx >> 3, ch = (idx & 7) * 8;
        *(bf16x8*)&Ks[row][ch] = *(const bf16x8*)(kbase + (size_t)(t0 + row) * D_ + ch);
        *(bf16x8*)&VT[row][ch] = *(const bf16x8*)(vtb + (size_t)row * S_ + t0 + ch);
      }
      if (tid < 64)
        kbias[tid] = maskp[b * S_ + t0 + tid] ? -23.08312f : -1.0e38f;
      __syncthreads();
      f32x4 sfr[4];
      for (int nb = 0; nb < 4; ++nb) sfr[nb] = (f32x4){0.f, 0.f, 0.f, 0.f};
      for (int nb = 0; nb < 4; ++nb)
        for (int ks = 0; ks < 2; ++ks) {
          bf16x8 bk = *(const bf16x8*)&Ks[l15 + 16 * nb][32 * ks + quad * 8];
          sfr[nb] = __builtin_amdgcn_mfma_f32_16x16x32_bf16(aq[ks], bk, sfr[nb], 0, 0, 0);
        }
      if (kt < qt) {                         // interior tiles: no causal test
        for (int nb = 0; nb < 4; ++nb) {
          const float bb = kbias[l15 + 16 * nb];
          for (int i = 0; i < 4; ++i)
            Pl[w][quad * 4 + i][l15 + 16 * nb] = f2bf_fast(exp2f(sfr[nb][i] * c2 + bb));
        }
      } else {                               // boundary tile: add causal mask
        for (int nb = 0; nb < 4; ++nb) {
          const int tg = l15 + 16 * nb;
          const float bb = kbias[l15 + 16 * nb];
          for (int i = 0; i < 4; ++i) {
            const float bbi = (tg > 16 * w + quad * 4 + i) ? -1.0e38f : bb;
            Pl[w][quad * 4 + i][l15 + 16 * nb] = f2bf_fast(exp2f(sfr[nb][i] * c2 + bbi));
          }
        }
      }
      asm volatile("s_waitcnt lgkmcnt(0)" ::: "memory");  // own-wave Pl writes
      bf16x8 ap0 = *(const bf16x8*)&Pl[w][l15][quad * 8];
      bf16x8 ap1 = *(const bf16x8*)&Pl[w][l15][32 + quad * 8];
      for (int no = 0; no < 4; ++no) {
        bf16x8 bv0 = *(const bf16x8*)&VT[16 * no + l15][quad * 8];
        bf16x8 bv1 = *(const bf16x8*)&VT[16 * no + l15][32 + quad * 8];
        o[no] = __builtin_amdgcn_mfma_f32_16x16x32_bf16(ap0, bv0, o[no], 0, 0, 0);
        o[no] = __builtin_amdgcn_mfma_f32_16x16x32_bf16(ap1, bv1, o[no], 0, 0, 0);
      }
      lsum = __builtin_amdgcn_mfma_f32_16x16x32_bf16(ap0, ones, lsum, 0, 0, 0);
      lsum = __builtin_amdgcn_mfma_f32_16x16x32_bf16(ap1, ones, lsum, 0, 0, 0);
    }
    // epilogue: write partials; kh=0 also writes V rows for masked queries
    for (int i = 0; i < 4; ++i) {
      const int s = r0 + 16 * w + quad * 4 + i;
      const int qm = maskp[b * S_ + s];
      const size_t row = (size_t)(b * S_ + s) * E_ + hd * D_;
      if (kh == 0 && !qm) {
        for (int no = 0; no < 4; ++no) {
          const int d = l15 + 16 * no;
          ob[row + d] = vtb[(size_t)d * S_ + s];
        }
      }
      for (int no = 0; no < 4; ++no)
        PB[row + l15 + 16 * no] = f2bf(o[no][i]);
      if (l15 == 0)
        LB[bh * S_ + s] = lsum[i];
    }
  }
}

// ---------------------------------------------------------------------------
// merge: ob[m][e] = (P0 + P1) / (l0 + l1) for unmasked rows
// ---------------------------------------------------------------------------
__global__ __launch_bounds__(256) void merge_kernel(
    const short* __restrict__ pb0, const short* __restrict__ pb1,
    const float* __restrict__ lb0, const float* __restrict__ lb1,
    const int* __restrict__ maskp, short* __restrict__ ob) {
  int idx = blockIdx.x * 256 + threadIdx.x;  // 8192*64 threads
  int m = idx >> 6, e = (idx & 63) * 8;
  if (!maskp[m]) return;                     // masked row: flash wrote V
  int b = m >> 11, s = m & (S_ - 1);
  int bh = b * 8 + (e >> 6);
  float l = lb0[bh * S_ + s] + lb1[bh * S_ + s];
  float inv = 1.f / l;
  bf16x8 p0 = *(const bf16x8*)&pb0[(size_t)m * E_ + e];
  bf16x8 p1 = *(const bf16x8*)&pb1[(size_t)m * E_ + e];
  bf16x8 r;
  for (int j = 0; j < 8; ++j)
    r[j] = f2bf((bf2f(p0[j]) + bf2f(p1[j])) * inv);
  *(bf16x8*)&ob[(size_t)m * E_ + e] = r;
}

extern "C" void kernel_launch(void* const* d_in, const int* in_sizes, int n_in,
                              void* d_out, int out_size, void* d_ws, size_t ws_size,
                              hipStream_t stream) {
  const float* x    = (const float*)d_in[0];
  const int*   mask = (const int*)d_in[1];
  const float* Win  = (const float*)d_in[2];
  const float* Wout = (const float*)d_in[3];
  float* out = (float*)d_out;

  short* Xb    = (short*)d_ws;               // 8192*512
  short* Winb  = Xb + 8192 * 512;            // 1536*512
  short* Woutb = Winb + 1536 * 512;          // 512*512
  short* qb    = Woutb + 512 * 512;          // 32*2048*64 each
  short* kb    = qb + 32 * 2048 * 64;
  short* vbT   = kb + 32 * 2048 * 64;        // [bh][d][s] transposed
  short* ob    = vbT + 32 * 2048 * 64;       // 8192*512
  short* pb0   = ob + 8192 * 512;            // partial O, half 0 (bf16)
  short* pb1   = pb0 + 8192 * 512;           // partial O, half 1
  float* lb0   = (float*)(pb1 + 8192 * 512); // lsum partials [32][2048]
  float* lb1   = lb0 + 32 * 2048;            // total ws ~61.3 MB

  cvt_all<<<5120, 256, 0, stream>>>(x, Win, Wout, Xb, Winb, Woutb);
  gemm_qkv_mfma<<<dim3(64, 24), 256, 0, stream>>>(Xb, Winb, qb, kb, vbT);
  flash_mfma<<<1024, 256, 0, stream>>>(qb, kb, vbT, mask, pb0, pb1, lb0, lb1, ob);
  merge_kernel<<<2048, 256, 0, stream>>>(pb0, pb1, lb0, lb1, mask, ob);
  gemm_out_mfma<<<dim3(64, 8), 256, 0, stream>>>(ob, Woutb, out);
}